// Round 13
// baseline (455.235 us; speedup 1.0000x reference)
//
#include <hip/hip_runtime.h>
#include <stdint.h>

typedef unsigned short u16;
typedef unsigned int u32;

#define NV 400000
#define KOFF 27
#define EPS_BN 1e-5f

#define INV_ELEMS (KOFF * NV)            // 10.8M
#define INV_BYTES (INV_ELEMS * 4)        // 43.2 MB
#define FEATSBF_OFF INV_BYTES            // bf16 feats: 51.2 MB
#define WT_OFF (FEATSBF_OFF + NV * 64 * 2)
#define STATS_OFF (WT_OFF + KOFF * 64 * 64 * 2)

#define CVT_BLOCKS 25000                 // NV*64/4/256
#define BUILD_BLOCKS 10547               // ceil(INV_ELEMS/4/256), 4 elems per thread
#define WT_BLOCKS 432                    // ceil(KOFF*4096/256)
#define PREP_BLOCKS (CVT_BLOCKS + BUILD_BLOCKS + WT_BLOCKS)

#define MAIN_BLOCKS 3125                 // NV / 128 rows per block (exact)

using short8 = __attribute__((ext_vector_type(8))) short;
using floatx16 = __attribute__((ext_vector_type(16))) float;

__device__ __forceinline__ u16 f2bf(float f) {
  u32 u = __float_as_uint(f);
  u += 0x7FFFu + ((u >> 16) & 1u);
  return (u16)(u >> 16);
}

// barrier that orders LDS (lgkmcnt) but does NOT drain vmcnt: global loads
// issued before it stay in flight across the barrier and are awaited by the
// compiler's counted vmcnt at their consuming use. (__syncthreads would emit
// s_waitcnt vmcnt(0) and expose the full gather latency every k-step.)
__device__ __forceinline__ void bar_lgkm() {
  asm volatile("s_waitcnt lgkmcnt(0)\n\ts_barrier" ::: "memory");
}

// ---------------- fused prep: cvt feats -> bf16 | build inv map (x4 vec) | transpose W ----------------
__global__ void k_prep(const float* __restrict__ feats, u16* __restrict__ featsBf,
                       const int* __restrict__ in_idx, const int* __restrict__ out_idx,
                       const float* __restrict__ mask, int* __restrict__ inv,
                       const float* __restrict__ W, u16* __restrict__ Wt) {
  const int b = blockIdx.x;
  const int tid = threadIdx.x;
  if (b < CVT_BLOCKS) {
    // feats fp32 -> bf16, one float4 per thread
    int i = b * 256 + tid;
    float4 v = ((const float4*)feats)[i];
    ushort4 o;
    o.x = f2bf(v.x); o.y = f2bf(v.y); o.z = f2bf(v.z); o.w = f2bf(v.w);
    ((ushort4*)featsBf)[i] = o;
  } else if (b < CVT_BLOCKS + BUILD_BLOCKS) {
    // inverse map: inv[k][out_idx] = in_idx, 4 elems/thread (16B loads).
    // NV % 4 == 0 -> an aligned group of 4 never crosses a k boundary.
    // Valid pairs are a prefix of each k-row -> branches are wave-uniform.
    int i4 = (b - CVT_BLOCKS) * 256 + tid;
    if (i4 < INV_ELEMS / 4) {
      float4 m = ((const float4*)mask)[i4];
      if (m.x != 0.0f || m.y != 0.0f || m.z != 0.0f || m.w != 0.0f) {
        int4 ii = ((const int4*)in_idx)[i4];
        int4 oo = ((const int4*)out_idx)[i4];
        int k = i4 / (NV / 4);
        int* invk = inv + k * NV;
        if (m.x != 0.0f) invk[oo.x] = ii.x;
        if (m.y != 0.0f) invk[oo.y] = ii.y;
        if (m.z != 0.0f) invk[oo.z] = ii.z;
        if (m.w != 0.0f) invk[oo.w] = ii.w;
      }
    }
  } else {
    // Wt[k][o][c] = bf16(W[k][c][o])
    int t = (b - CVT_BLOCKS - BUILD_BLOCKS) * 256 + tid;
    if (t < KOFF * 64 * 64) {
      int k = t >> 12, rem = t & 4095, c = rem >> 6, o = rem & 63;
      Wt[(k << 12) + (o << 6) + c] = f2bf(W[t]);
    }
  }
}

// ---------------- main: 32x64 wave tile, lgkm-only barriers (vmcnt never drained) ----------------
// Round-8 structure (32 AGPR acc + 32 VGPR A-frags -> 4 waves/SIMD, occupancy 35%)
// with ONE change: in-loop __syncthreads() -> bar_lgkm(). Round 8 showed occupancy
// doubling changed nothing (127.5us, MfmaUtil 29% at both 2 and 4 waves/SIMD):
// the limiter is the vmcnt(0) drain each barrier forced on the just-issued A-gather
// (~500-900 cyc L3 latency exposed per k-step). With lgkm-only barriers the gather
// stays in flight a full k-step and drains at its counted consuming wait.
__global__ void __launch_bounds__(256, 4)
k_main(const u16* __restrict__ feats, const int* __restrict__ inv,
       const u16* __restrict__ Wt, float* __restrict__ out, float* __restrict__ stats) {
  __shared__ u16 Wsm[2][64][72];   // 72-pitch: conflict-free frag reads (measured 0)
  __shared__ float redS[4][64];
  __shared__ float redQ[4][64];

  const int t = threadIdx.x;
  const int lane = t & 63;
  const int wave = t >> 6;
  const int lo = lane & 31;        // A row within the 32-row tile / D col within 32-col group
  const int hi = lane >> 5;        // k-half selector of the fragment
  const int rbase = blockIdx.x * 128 + wave * 32;
  const int row = rbase + lo;      // always < NV: 3125 * 128 == NV

  const floatx16 z16 = {0.f, 0.f, 0.f, 0.f, 0.f, 0.f, 0.f, 0.f,
                        0.f, 0.f, 0.f, 0.f, 0.f, 0.f, 0.f, 0.f};
  floatx16 acc0 = z16, acc1 = z16;   // cols 0-31 / 32-63

  const int wr0 = t >> 3;          // staging: row within tile
  const int wc0 = (t & 7) * 8;     // staging: col (u16 units)

#define GATHER(A, s)                                                  \
  {                                                                   \
    const short8 z8 = {0, 0, 0, 0, 0, 0, 0, 0};                       \
    A[0] = z8; A[1] = z8; A[2] = z8; A[3] = z8;                       \
    if ((s) >= 0) {                                                   \
      const u16* p = feats + (s) * 64 + hi * 8;                       \
      A[0] = *(const short8*)(p);                                     \
      A[1] = *(const short8*)(p + 16);                                \
      A[2] = *(const short8*)(p + 32);                                \
      A[3] = *(const short8*)(p + 48);                                \
    }                                                                 \
  }

#define DOMFMA(BUF, A)                                                          \
  _Pragma("unroll")                                                             \
  for (int kk = 0; kk < 4; ++kk) {                                              \
    short8 b0 = *(const short8*)&Wsm[BUF][lo][kk * 16 + hi * 8];                \
    short8 b1 = *(const short8*)&Wsm[BUF][32 + lo][kk * 16 + hi * 8];           \
    acc0 = __builtin_amdgcn_mfma_f32_32x32x16_bf16(A[kk], b0, acc0, 0, 0, 0);   \
    acc1 = __builtin_amdgcn_mfma_f32_32x32x16_bf16(A[kk], b1, acc1, 0, 0, 0);   \
  }

  // ---- prologue: W tile 0 in regs, srcs for tiles 0/1, gather A tile 0 ----
  uint4 wEa = *(const uint4*)(Wt + t * 8);
  uint4 wEb = *(const uint4*)(Wt + (t + 256) * 8);
  uint4 wOa = wEa, wOb = wEb;
  int sC = inv[row];
  short8 Ac[4], An[4];
  GATHER(Ac, sC);
  int sO = inv[NV + row];          // src for tile 1
  int sE = -1;

  for (int k = 0; k < KOFF; k += 2) {
    // -------- even step: tile k in buf 0 --------
    *(uint4*)&Wsm[0][wr0][wc0] = wEa;
    *(uint4*)&Wsm[0][wr0 + 32][wc0] = wEb;
    if (k + 1 < KOFF) {
      const u16* wk = Wt + ((k + 1) << 12);
      wOa = *(const uint4*)(wk + t * 8);
      wOb = *(const uint4*)(wk + (t + 256) * 8);
    }
    if (k + 2 < KOFF) sE = inv[(k + 2) * NV + row];
    if (k + 1 < KOFF) GATHER(An, sO);   // A for tile k+1 (in flight across barrier)
    bar_lgkm();
    DOMFMA(0, Ac);
    if (k + 1 >= KOFF) break;
    // -------- odd step: tile k+1 in buf 1 --------
    *(uint4*)&Wsm[1][wr0][wc0] = wOa;
    *(uint4*)&Wsm[1][wr0 + 32][wc0] = wOb;
    if (k + 2 < KOFF) {
      const u16* wk = Wt + ((k + 2) << 12);
      wEa = *(const uint4*)(wk + t * 8);
      wEb = *(const uint4*)(wk + (t + 256) * 8);
    }
    if (k + 3 < KOFF) sO = inv[(k + 3) * NV + row];
    if (k + 2 < KOFF) GATHER(Ac, sE);   // A for tile k+2 (in flight across barrier)
    bar_lgkm();
    DOMFMA(1, An);
  }
#undef GATHER
#undef DOMFMA

  // fused channel stats: lane holds col lo (acc0) / 32+lo (acc1); rows split across hi
  float s0 = 0.f, q0 = 0.f, s1 = 0.f, q1 = 0.f;
#pragma unroll
  for (int r = 0; r < 16; ++r) {
    s0 += acc0[r];
    q0 += acc0[r] * acc0[r];
    s1 += acc1[r];
    q1 += acc1[r] * acc1[r];
  }
  s0 += __shfl_xor(s0, 32, 64); q0 += __shfl_xor(q0, 32, 64);
  s1 += __shfl_xor(s1, 32, 64); q1 += __shfl_xor(q1, 32, 64);
  if (lane < 32) {
    redS[wave][lo] = s0; redQ[wave][lo] = q0;
    redS[wave][32 + lo] = s1; redQ[wave][32 + lo] = q1;
  }

  // epilogue: write pre-BN fp32. D layout: col = lane&31, row = (r&3) + 8*(r>>2) + 4*hi
#pragma unroll
  for (int r = 0; r < 16; ++r) {
    int rl = (r & 3) + ((r >> 2) * 8) + hi * 4;
    int ra = rbase + rl;
    out[ra * 64 + lo] = acc0[r];
    out[ra * 64 + 32 + lo] = acc1[r];
  }

  __syncthreads();
  if (t < 64) {
    float s = redS[0][t] + redS[1][t] + redS[2][t] + redS[3][t];
    float q = redQ[0][t] + redQ[1][t] + redQ[2][t] + redQ[3][t];
    atomicAdd(&stats[t], s);
    atomicAdd(&stats[64 + t], q);
  }
}

// ---------------- apply BN + ReLU in place (stats finalize fused per block) ----------------
__global__ void k_apply(float* __restrict__ out, const float* __restrict__ stats,
                        const float* __restrict__ gamma, const float* __restrict__ beta) {
  __shared__ float sc[64], sh[64];
  const int t = threadIdx.x;
  if (t < 64) {
    float inv_n = 1.0f / (float)NV;
    float mean = stats[t] * inv_n;
    float var = stats[64 + t] * inv_n - mean * mean;
    float scale = gamma[t] * rsqrtf(var + EPS_BN);
    sc[t] = scale;
    sh[t] = beta[t] - mean * scale;
  }
  __syncthreads();
  int i = blockIdx.x * 256 + t;   // one float4 per thread
  if (i >= NV * 64 / 4) return;
  int c0 = (i & 15) * 4;
  float4 v = ((const float4*)out)[i];
  float* pv = (float*)&v;
#pragma unroll
  for (int j = 0; j < 4; ++j) {
    float y = pv[j] * sc[c0 + j] + sh[c0 + j];
    pv[j] = y > 0.f ? y : 0.f;
  }
  ((float4*)out)[i] = v;
}

extern "C" void kernel_launch(void* const* d_in, const int* in_sizes, int n_in,
                              void* d_out, int out_size, void* d_ws, size_t ws_size,
                              hipStream_t stream) {
  const float* feats = (const float*)d_in[0];
  const float* W     = (const float*)d_in[1];
  const float* gamma = (const float*)d_in[2];
  const float* beta  = (const float*)d_in[3];
  const float* mask  = (const float*)d_in[4];
  const int* in_idx  = (const int*)d_in[5];
  const int* out_idx = (const int*)d_in[6];
  float* out = (float*)d_out;

  char* ws = (char*)d_ws;
  int* inv = (int*)ws;                        // 43.2 MB
  u16* featsBf = (u16*)(ws + FEATSBF_OFF);    // 51.2 MB
  u16* Wt = (u16*)(ws + WT_OFF);              // 216 KB
  float* stats = (float*)(ws + STATS_OFF);    // 128 floats used

  hipMemsetAsync(inv, 0xFF, INV_BYTES, stream);              // inv = -1
  hipMemsetAsync(stats, 0, 128 * sizeof(float), stream);     // sum/sq = 0
  k_prep<<<PREP_BLOCKS, 256, 0, stream>>>(feats, featsBf, in_idx, out_idx, mask, inv, W, Wt);
  k_main<<<MAIN_BLOCKS, 256, 0, stream>>>(featsBf, inv, Wt, out, stats);
  k_apply<<<NV * 64 / 4 / 256, 256, 0, stream>>>(out, stats, gamma, beta);
}

// Round 15
// 412.212 us; speedup vs baseline: 1.1044x; 1.1044x over previous
//
#include <hip/hip_runtime.h>
#include <stdint.h>

typedef unsigned short u16;
typedef unsigned int u32;

#define NV 400000
#define KOFF 27
#define EPS_BN 1e-5f

#define INV_ELEMS (KOFF * NV)            // 10.8M
#define INV_BYTES (INV_ELEMS * 4)        // 43.2 MB
#define FEATSBF_OFF INV_BYTES            // bf16 feats: 51.2 MB
#define WT_OFF (FEATSBF_OFF + NV * 64 * 2)
#define STATS_OFF (WT_OFF + KOFF * 64 * 64 * 2)

// grid-stride work-item counts for the fused prep kernel
#define CVT_ITEMS (NV * 64 / 4)          // 6.4M float4s
#define BUILD_ITEMS INV_ELEMS            // 10.8M pairs
#define WT_ITEMS (KOFF * 64 * 64)        // 110592
#define PREP_TOTAL (CVT_ITEMS + BUILD_ITEMS + WT_ITEMS)
#define PREP_GRID 3072
#define APPLY_GRID 2048

#define MAIN_BLOCKS 3125                 // NV / 128 rows per block (exact)

using short8 = __attribute__((ext_vector_type(8))) short;
using floatx16 = __attribute__((ext_vector_type(16))) float;

__device__ __forceinline__ u16 f2bf(float f) {
  u32 u = __float_as_uint(f);
  u += 0x7FFFu + ((u >> 16) & 1u);
  return (u16)(u >> 16);
}

// ---------------- fused prep (grid-stride, G11: cap blocks, amortize per-block cost) ----------------
// sections: cvt feats fp32->bf16 | build inverse map | transpose+convert W
__global__ void k_prep(const float* __restrict__ feats, u16* __restrict__ featsBf,
                       const int* __restrict__ in_idx, const int* __restrict__ out_idx,
                       const float* __restrict__ mask, int* __restrict__ inv,
                       const float* __restrict__ W, u16* __restrict__ Wt) {
  const int stride = PREP_GRID * 256;
  for (int i = blockIdx.x * 256 + threadIdx.x; i < PREP_TOTAL; i += stride) {
    if (i < CVT_ITEMS) {
      float4 v = ((const float4*)feats)[i];
      ushort4 o;
      o.x = f2bf(v.x); o.y = f2bf(v.y); o.z = f2bf(v.z); o.w = f2bf(v.w);
      ((ushort4*)featsBf)[i] = o;
    } else if (i < CVT_ITEMS + BUILD_ITEMS) {
      int t = i - CVT_ITEMS;
      if (mask[t] != 0.0f) {
        int k = t / NV;
        inv[k * NV + out_idx[t]] = in_idx[t];
      }
    } else {
      int t = i - CVT_ITEMS - BUILD_ITEMS;
      int k = t >> 12, rem = t & 4095, c = rem >> 6, o = rem & 63;
      Wt[(k << 12) + (o << 6) + c] = f2bf(W[t]);
    }
  }
}

// ---------------- main: 32x64 wave tile, per-k double-buffered W (verified 127.5us) ----------------
// BYTE-IDENTICAL to the round-8 source verified at 403.5us total / 127.5us k_main.
// (lgkm inline-asm barrier variant spilled ~22MB to scratch and regressed; reverted.)
// 32 AGPR acc + ~28 VGPR A-frags -> 60 VGPR reported, 4 waves/SIMD, occupancy ~35%.
// W tile reg-prefetched -> LDS (72-pitch, 0 bank conflicts); A gathered straight to
// MFMA fragment regs 1 tile ahead; inv srcs 2 tiles ahead.
__global__ void __launch_bounds__(256, 4)
k_main(const u16* __restrict__ feats, const int* __restrict__ inv,
       const u16* __restrict__ Wt, float* __restrict__ out, float* __restrict__ stats) {
  __shared__ u16 Wsm[2][64][72];   // 72-pitch: conflict-free frag reads (measured 0)
  __shared__ float redS[4][64];
  __shared__ float redQ[4][64];

  const int t = threadIdx.x;
  const int lane = t & 63;
  const int wave = t >> 6;
  const int lo = lane & 31;        // A row within the 32-row tile / D col within 32-col group
  const int hi = lane >> 5;        // k-half selector of the fragment
  const int rbase = blockIdx.x * 128 + wave * 32;
  const int row = rbase + lo;      // always < NV: 3125 * 128 == NV

  const floatx16 z16 = {0.f, 0.f, 0.f, 0.f, 0.f, 0.f, 0.f, 0.f,
                        0.f, 0.f, 0.f, 0.f, 0.f, 0.f, 0.f, 0.f};
  floatx16 acc0 = z16, acc1 = z16;   // cols 0-31 / 32-63

  const int wr0 = t >> 3;          // staging: row within tile
  const int wc0 = (t & 7) * 8;     // staging: col (u16 units)

#define GATHER(A, s)                                                  \
  {                                                                   \
    const short8 z8 = {0, 0, 0, 0, 0, 0, 0, 0};                       \
    A[0] = z8; A[1] = z8; A[2] = z8; A[3] = z8;                       \
    if ((s) >= 0) {                                                   \
      const u16* p = feats + (s) * 64 + hi * 8;                       \
      A[0] = *(const short8*)(p);                                     \
      A[1] = *(const short8*)(p + 16);                                \
      A[2] = *(const short8*)(p + 32);                                \
      A[3] = *(const short8*)(p + 48);                                \
    }                                                                 \
  }

#define DOMFMA(BUF, A)                                                          \
  _Pragma("unroll")                                                             \
  for (int kk = 0; kk < 4; ++kk) {                                              \
    short8 b0 = *(const short8*)&Wsm[BUF][lo][kk * 16 + hi * 8];                \
    short8 b1 = *(const short8*)&Wsm[BUF][32 + lo][kk * 16 + hi * 8];           \
    acc0 = __builtin_amdgcn_mfma_f32_32x32x16_bf16(A[kk], b0, acc0, 0, 0, 0);   \
    acc1 = __builtin_amdgcn_mfma_f32_32x32x16_bf16(A[kk], b1, acc1, 0, 0, 0);   \
  }

  // ---- prologue: W tile 0 in regs, srcs for tiles 0/1, gather A tile 0 ----
  uint4 wEa = *(const uint4*)(Wt + t * 8);
  uint4 wEb = *(const uint4*)(Wt + (t + 256) * 8);
  uint4 wOa = wEa, wOb = wEb;
  int sC = inv[row];
  short8 Ac[4], An[4];
  GATHER(Ac, sC);
  int sO = inv[NV + row];          // src for tile 1
  int sE = -1;

  for (int k = 0; k < KOFF; k += 2) {
    // -------- even step: tile k in buf 0 --------
    *(uint4*)&Wsm[0][wr0][wc0] = wEa;
    *(uint4*)&Wsm[0][wr0 + 32][wc0] = wEb;
    if (k + 1 < KOFF) {
      const u16* wk = Wt + ((k + 1) << 12);
      wOa = *(const uint4*)(wk + t * 8);
      wOb = *(const uint4*)(wk + (t + 256) * 8);
    }
    if (k + 2 < KOFF) sE = inv[(k + 2) * NV + row];
    if (k + 1 < KOFF) GATHER(An, sO);   // A for tile k+1
    __syncthreads();
    DOMFMA(0, Ac);
    if (k + 1 >= KOFF) break;
    // -------- odd step: tile k+1 in buf 1 --------
    *(uint4*)&Wsm[1][wr0][wc0] = wOa;
    *(uint4*)&Wsm[1][wr0 + 32][wc0] = wOb;
    if (k + 2 < KOFF) {
      const u16* wk = Wt + ((k + 2) << 12);
      wEa = *(const uint4*)(wk + t * 8);
      wEb = *(const uint4*)(wk + (t + 256) * 8);
    }
    if (k + 3 < KOFF) sO = inv[(k + 3) * NV + row];
    if (k + 2 < KOFF) GATHER(Ac, sE);   // A for tile k+2
    __syncthreads();
    DOMFMA(1, An);
  }
#undef GATHER
#undef DOMFMA

  // fused channel stats: lane holds col lo (acc0) / 32+lo (acc1); rows split across hi
  float s0 = 0.f, q0 = 0.f, s1 = 0.f, q1 = 0.f;
#pragma unroll
  for (int r = 0; r < 16; ++r) {
    s0 += acc0[r];
    q0 += acc0[r] * acc0[r];
    s1 += acc1[r];
    q1 += acc1[r] * acc1[r];
  }
  s0 += __shfl_xor(s0, 32, 64); q0 += __shfl_xor(q0, 32, 64);
  s1 += __shfl_xor(s1, 32, 64); q1 += __shfl_xor(q1, 32, 64);
  if (lane < 32) {
    redS[wave][lo] = s0; redQ[wave][lo] = q0;
    redS[wave][32 + lo] = s1; redQ[wave][32 + lo] = q1;
  }

  // epilogue: write pre-BN fp32. D layout: col = lane&31, row = (r&3) + 8*(r>>2) + 4*hi
#pragma unroll
  for (int r = 0; r < 16; ++r) {
    int rl = (r & 3) + ((r >> 2) * 8) + hi * 4;
    int ra = rbase + rl;
    out[ra * 64 + lo] = acc0[r];
    out[ra * 64 + 32 + lo] = acc1[r];
  }

  __syncthreads();
  if (t < 64) {
    float s = redS[0][t] + redS[1][t] + redS[2][t] + redS[3][t];
    float q = redQ[0][t] + redQ[1][t] + redQ[2][t] + redQ[3][t];
    atomicAdd(&stats[t], s);
    atomicAdd(&stats[64 + t], q);
  }
}

// ---------------- apply BN + ReLU in place (grid-stride, stats finalize per block) ----------------
__global__ void k_apply(float* __restrict__ out, const float* __restrict__ stats,
                        const float* __restrict__ gamma, const float* __restrict__ beta) {
  __shared__ float sc[64], sh[64];
  const int t = threadIdx.x;
  if (t < 64) {
    float inv_n = 1.0f / (float)NV;
    float mean = stats[t] * inv_n;
    float var = stats[64 + t] * inv_n - mean * mean;
    float scale = gamma[t] * rsqrtf(var + EPS_BN);
    sc[t] = scale;
    sh[t] = beta[t] - mean * scale;
  }
  __syncthreads();
  const int stride = APPLY_GRID * 256;
  for (int i = blockIdx.x * 256 + t; i < NV * 64 / 4; i += stride) {
    int c0 = (i & 15) * 4;
    float4 v = ((const float4*)out)[i];
    float* pv = (float*)&v;
#pragma unroll
    for (int j = 0; j < 4; ++j) {
      float y = pv[j] * sc[c0 + j] + sh[c0 + j];
      pv[j] = y > 0.f ? y : 0.f;
    }
    ((float4*)out)[i] = v;
  }
}

extern "C" void kernel_launch(void* const* d_in, const int* in_sizes, int n_in,
                              void* d_out, int out_size, void* d_ws, size_t ws_size,
                              hipStream_t stream) {
  const float* feats = (const float*)d_in[0];
  const float* W     = (const float*)d_in[1];
  const float* gamma = (const float*)d_in[2];
  const float* beta  = (const float*)d_in[3];
  const float* mask  = (const float*)d_in[4];
  const int* in_idx  = (const int*)d_in[5];
  const int* out_idx = (const int*)d_in[6];
  float* out = (float*)d_out;

  char* ws = (char*)d_ws;
  int* inv = (int*)ws;                        // 43.2 MB
  u16* featsBf = (u16*)(ws + FEATSBF_OFF);    // 51.2 MB
  u16* Wt = (u16*)(ws + WT_OFF);              // 216 KB
  float* stats = (float*)(ws + STATS_OFF);    // 128 floats used

  hipMemsetAsync(inv, 0xFF, INV_BYTES, stream);              // inv = -1
  hipMemsetAsync(stats, 0, 128 * sizeof(float), stream);     // sum/sq = 0
  k_prep<<<PREP_GRID, 256, 0, stream>>>(feats, featsBf, in_idx, out_idx, mask, inv, W, Wt);
  k_main<<<MAIN_BLOCKS, 256, 0, stream>>>(featsBf, inv, Wt, out, stats);
  k_apply<<<APPLY_GRID, 256, 0, stream>>>(out, stats, gamma, beta);
}